// Round 2
// baseline (247.479 us; speedup 1.0000x reference)
//
#include <hip/hip_runtime.h>
#include <hip/hip_cooperative_groups.h>

// NCN recurrence, 2 layers. B=4, N=4096, E=128, NK=4, ce=32, CACHE=32, m=128.
// 2048 independent [32 rows x 32 feats] subproblems per layer.
//
// R11: FUSED COOPERATIVE KERNEL. R10 evidence: a full restructure moved
// dur_us 119.9 -> 119.2 while both ncn dispatches stayed below the 44.5us
// poison fills (2x 256MiB fillBufferAligned = ~89us) -> the timed region is
// dominated by harness re-poison + restore; our kernels are ~25-30us total.
// Remaining levers that are OURS: inter-dispatch gap, 32MB mid-state HBM
// round trip, unscale/rescale between layers. Fuse both layers into ONE
// cooperative kernel:
//   - layer 0 (s=0): d_in -> d_out, stored in SCALED domain (no unscale)
//   - __threadfence() + grid.sync() (device-scope visibility across XCDs)
//   - layer 1 (s=1): d_out -> d_out IN-PLACE (safe: the group/row mapping is
//     a bijection and feat slices are disjoint per n -> each address has
//     exactly one reader == its writer; reads precede writes per lane)
// d_ws is no longer used at all.
//
// Per-layer structure unchanged from R10 (wave-autonomous groups):
//   lane l: row r = l>>1, feat half h = l&1 (16 feats = 8 f32x2).
//   row-j broadcast: 16x ds_bpermute (imm-folded addr), no LDS/barriers.
//   pair reduce via DPP quad_perm; row-j Wj-dot via v_readlane (imm lane).
//   scaled domain: Xi = L1*xi, Ya = 0.1*L1*xa, W pre-scaled by ln2;
//   tanh = 1 - 2/(exp2(arg)+1), arg = Xi + sim*Xj (exact +-1 at overflow).
// Grid 512 x 256 = 2048 waves = 2 blocks/CU (exactly co-resident at
// __launch_bounds__(256,2), VGPR cap 256 >> actual ~120).

namespace {
constexpr int kB = 4;
constexpr int kN = 4096;
constexpr int kE = 128;
constexpr int kCE = 32;          // E / NK
constexpr int kCache = 32;
constexpr int kM = kN / kCache;  // 128 groups per batch

constexpr float kL1    = 1.4426950408889634f;   // log2(e)
constexpr float kInvL1 = 0.6931471805599453f;   // ln(2)

typedef __attribute__((ext_vector_type(2))) float f32x2;

__device__ __forceinline__ f32x2 pk_fma(f32x2 a, f32x2 b, f32x2 c) {
    return __builtin_elementwise_fma(a, b, c);
}

// x + partner(l^1)'s x via DPP quad_perm [1,0,3,2] — no LDS roundtrip.
__device__ __forceinline__ float pair_sum(float x) {
    int sw = __builtin_amdgcn_update_dpp(0, __float_as_int(x),
                                         0xB1, 0xF, 0xF, true);
    return x + __int_as_float(sw);
}

// pull both halves of an f32x2 from lane (byte_addr >> 2)
__device__ __forceinline__ f32x2 bperm2(int byte_addr, f32x2 v) {
    f32x2 r;
    r.x = __int_as_float(
        __builtin_amdgcn_ds_bpermute(byte_addr, __float_as_int(v.x)));
    r.y = __int_as_float(
        __builtin_amdgcn_ds_bpermute(byte_addr, __float_as_int(v.y)));
    return r;
}

// One NCN layer for one (b,g,n) unit, executed by one wave.
// S: group stride (0 for stage 0, 1 for stage 1).
// IN_SCALED:  inputs already in scaled domain (Xi = L1*x, Ya = 0.1*L1*xa).
// OUT_SCALED: leave outputs in scaled domain (skip unscale).
template <int S, bool IN_SCALED, bool OUT_SCALED>
__device__ __forceinline__ void ncn_layer(
    const float* x_in, const float* xa_in, const float* Wl,
    float* x_out, float* xa_out, int unit, int l)
{
    const int n = unit & 3;
    const int g = (unit >> 2) & (kM - 1);
    const int b = unit >> 9;

    const int h = l & 1;                        // feat half: [h*16, h*16+16)
    const int r = l >> 1;                       // row in group, 0..31

    // global row: ((g + r*S) % m) * CACHE + r
    const int gr = (((g + r * S) & (kM - 1)) << 5) + r;
    const size_t base = ((size_t)(b * kN + gr)) * kE + n * kCE + h * 16;

    // state (scaled domain) + weights (pre-scaled by ln2 -> dots = TRUE sim)
    f32x2 xi[8], ya[8], wi[8], wj[8];
    {
        const float4* xi4 = reinterpret_cast<const float4*>(x_in + base);
        const float4* xa4 = reinterpret_cast<const float4*>(xa_in + base);
        const float4* wi4 = reinterpret_cast<const float4*>(Wl + n * kCE + h * 16);
        const float4* wj4 = reinterpret_cast<const float4*>(Wl + kE + n * kCE + h * 16);
#pragma unroll
        for (int q4 = 0; q4 < 4; ++q4) {
            float4 v = xi4[q4];
            float4 a = xa4[q4];
            if constexpr (IN_SCALED) {
                xi[2 * q4 + 0] = f32x2{v.x, v.y};
                xi[2 * q4 + 1] = f32x2{v.z, v.w};
                ya[2 * q4 + 0] = f32x2{a.x, a.y};
                ya[2 * q4 + 1] = f32x2{a.z, a.w};
            } else {
                xi[2 * q4 + 0] = f32x2{v.x * kL1, v.y * kL1};
                xi[2 * q4 + 1] = f32x2{v.z * kL1, v.w * kL1};
                ya[2 * q4 + 0] = f32x2{a.x * (0.1f * kL1), a.y * (0.1f * kL1)};
                ya[2 * q4 + 1] = f32x2{a.z * (0.1f * kL1), a.w * (0.1f * kL1)};
            }
            float4 u = wi4[q4];
            wi[2 * q4 + 0] = f32x2{u.x * kInvL1, u.y * kInvL1};
            wi[2 * q4 + 1] = f32x2{u.z * kInvL1, u.w * kInvL1};
            float4 w2 = wj4[q4];
            wj[2 * q4 + 0] = f32x2{w2.x * kInvL1, w2.y * kInvL1};
            wj[2 * q4 + 1] = f32x2{w2.z * kInvL1, w2.w * kInvL1};
        }
    }

    const int v4h = h << 2;                     // bpermute byte base (lane*4)

    const f32x2 one = {1.0f, 1.0f};
    const f32x2 c9  = {0.9f, 0.9f};
    const f32x2 cA  = {0.01f * kL1, 0.01f * kL1};      // + 0.01*L1
    const f32x2 cB  = {-0.02f * kL1, -0.02f * kL1};    // - 0.02*L1 * rc

#pragma unroll
    for (int j = 0; j < kCache; ++j) {
        // (1) pull row j's own-half feats from lanes 2j / 2j+1 (pre-update
        //     state: program order guarantees all lanes are at step j)
        const int addr = v4h + 8 * j;           // folds to offset imm
        f32x2 xj[8];
#pragma unroll
        for (int q = 0; q < 8; ++q) xj[q] = bperm2(addr, xi[q]);

        // (2) own-row dots over own 16 feats (true domain):
        //     a = xi_r . Wi   e = xi_r . Wj
        f32x2 a0 = xi[0] * wi[0], a1 = xi[1] * wi[1];
        f32x2 e0 = xi[0] * wj[0], e1 = xi[1] * wj[1];
        a0 = pk_fma(xi[2], wi[2], a0); a1 = pk_fma(xi[3], wi[3], a1);
        e0 = pk_fma(xi[2], wj[2], e0); e1 = pk_fma(xi[3], wj[3], e1);
        a0 = pk_fma(xi[4], wi[4], a0); a1 = pk_fma(xi[5], wi[5], a1);
        e0 = pk_fma(xi[4], wj[4], e0); e1 = pk_fma(xi[5], wj[5], e1);
        a0 = pk_fma(xi[6], wi[6], a0); a1 = pk_fma(xi[7], wi[7], a1);
        e0 = pk_fma(xi[6], wj[6], e0); e1 = pk_fma(xi[7], wj[7], e1);
        f32x2 av = a0 + a1, ev = e0 + e1;
        float a = av.x + av.y;
        float e = ev.x + ev.y;
        a = pair_sum(a);                        // full 32-feat row dot
        e = pair_sum(e);

        // (3) row j's Wj-dot: one readlane (lane 2j holds it), uniform scalar
        const float dj = __int_as_float(
            __builtin_amdgcn_readlane(__float_as_int(e), 2 * j));
        const float sim = a + dj;               // true sim for this row
        const f32x2 sv = {sim, sim};

        // (4) elementwise update in scaled domain
#pragma unroll
        for (int q = 0; q < 8; ++q) {
            f32x2 arg = pk_fma(xj[q], sv, xi[q]);   // L1*(xi + sim*xj) = L1*2T
            f32x2 t2;
            t2.x = __builtin_amdgcn_exp2f(arg.x);
            t2.y = __builtin_amdgcn_exp2f(arg.y);
            f32x2 den = t2 + one;
            f32x2 rc;
            rc.x = __builtin_amdgcn_rcpf(den.x);
            rc.y = __builtin_amdgcn_rcpf(den.y);
            // Ya' = 0.9*Ya + 0.01*L1 - 0.02*L1*rc   (Ya = 0.1*L1*xa)
            f32x2 yt = pk_fma(ya[q], c9, cA);
            ya[q] = pk_fma(rc, cB, yt);
            // Xi' = 0.9*Xi + Ya'
            xi[q] = pk_fma(xi[q], c9, ya[q]);
        }
    }

    // epilogue
    {
        float4* xo4 = reinterpret_cast<float4*>(x_out + base);
        float4* ao4 = reinterpret_cast<float4*>(xa_out + base);
#pragma unroll
        for (int q4 = 0; q4 < 4; ++q4) {
            f32x2 x0 = xi[2 * q4 + 0], x1 = xi[2 * q4 + 1];
            f32x2 a0 = ya[2 * q4 + 0], a1 = ya[2 * q4 + 1];
            if constexpr (!OUT_SCALED) {
                const f32x2 ivx = {kInvL1, kInvL1};
                const f32x2 iva = {10.0f * kInvL1, 10.0f * kInvL1};
                x0 = x0 * ivx; x1 = x1 * ivx;
                a0 = a0 * iva; a1 = a1 * iva;
            }
            float4 v; v.x = x0.x; v.y = x0.y; v.z = x1.x; v.w = x1.y;
            xo4[q4] = v;
            float4 w; w.x = a0.x; w.y = a0.y; w.z = a1.x; w.w = a1.y;
            ao4[q4] = w;
        }
    }
}
}  // namespace

__global__ void __launch_bounds__(256, 2) ncn_fused_kernel(
    const float* __restrict__ x, const float* __restrict__ xa,
    const float* __restrict__ W,
    float* __restrict__ xo, float* __restrict__ ao)
{
    const int t = threadIdx.x;
    const int unit = blockIdx.x * 4 + (t >> 6);   // (b, g, n), 0..2047
    const int l = t & 63;

    // Layer 0 (stage 0): d_in -> d_out, scaled-domain mid-state.
    ncn_layer<0, false, true>(x, xa, W, xo, ao, unit, l);

    // Device-scope visibility (cross-XCD L2s are non-coherent) + grid barrier.
    __threadfence();
    cooperative_groups::this_grid().sync();

    // Layer 1 (stage 1): d_out -> d_out in-place (reader == writer per addr).
    ncn_layer<1, true, false>(xo, ao, W + 2 * kE, xo, ao, unit, l);
}

extern "C" void kernel_launch(void* const* d_in, const int* in_sizes, int n_in,
                              void* d_out, int out_size, void* d_ws, size_t ws_size,
                              hipStream_t stream) {
    const float* x  = (const float*)d_in[0];   // [B, N, E] fp32
    const float* xa = (const float*)d_in[1];   // [B, N, E] fp32
    const float* W  = (const float*)d_in[2];   // [2, 256] fp32

    const size_t plane = (size_t)kB * kN * kE;   // 2,097,152 floats (8 MiB)

    float* x_out  = (float*)d_out;               // final outputs
    float* xa_out = x_out + plane;

    // 512 blocks x 256 threads = 2048 waves = 2 blocks/CU, exactly co-resident.
    void* args[5] = {(void*)&x, (void*)&xa, (void*)&W,
                     (void*)&x_out, (void*)&xa_out};
    hipLaunchCooperativeKernel((const void*)ncn_fused_kernel,
                               dim3(kB * kM), dim3(256), args, 0, stream);
}

// Round 3
// 185.926 us; speedup vs baseline: 1.3311x; 1.3311x over previous
//
#include <hip/hip_runtime.h>

// NCN recurrence, 2 layers. B=4, N=4096, E=128, NK=4, ce=32, CACHE=32, m=128.
// 2048 independent [32 rows x 32 feats] subproblems per layer.
//
// R12: FUSED KERNEL, INLINE GRID BARRIER. R11 (fused via
// cooperative_groups::this_grid().sync()) ran 176us/dispatch at VGPR=60 —
// the per-layer state (~110 regs live) was spilled to scratch. Diagnosis:
// this_grid().sync() lowers to an opaque __ockl_grid_sync CALL, making the
// kernel non-leaf and wrecking regalloc (R10's identical layer code with no
// call didn't spill: two-dispatch total ~48us). Fix: hand-rolled grid
// barrier, 100% inline builtins (fence/atomic/s_sleep), counter in d_ws[0]
// zeroed by hipMemsetAsync each launch (graph-capturable). Co-residency
// still guaranteed by hipLaunchCooperativeKernel (512 blocks = 2/CU exact).
//
//   - layer 0 (s=0): d_in -> d_out, stored in SCALED domain (no unscale)
//   - inline grid barrier (release-fence + atomicAdd + spin + acquire-fence)
//   - layer 1 (s=1): d_out -> d_out IN-PLACE (the group/row map is a
//     bijection and feat slices are disjoint per n -> each address has
//     exactly one reader == its writer; reads precede writes per lane)
//
// Per-layer structure unchanged from R10 (wave-autonomous groups):
//   lane l: row r = l>>1, feat half h = l&1 (16 feats = 8 f32x2).
//   row-j broadcast: 16x ds_bpermute (imm-folded addr), no LDS/barriers.
//   pair reduce via DPP quad_perm; row-j Wj-dot via v_readlane (imm lane).
//   scaled domain: Xi = L1*xi, Ya = 0.1*L1*xa, W pre-scaled by ln2;
//   tanh = 1 - 2/(exp2(arg)+1), arg = Xi + sim*Xj (exact +-1 at overflow).

namespace {
constexpr int kB = 4;
constexpr int kN = 4096;
constexpr int kE = 128;
constexpr int kCE = 32;          // E / NK
constexpr int kCache = 32;
constexpr int kM = kN / kCache;  // 128 groups per batch
constexpr int kGrid = kB * kM;   // 512 blocks

constexpr float kL1    = 1.4426950408889634f;   // log2(e)
constexpr float kInvL1 = 0.6931471805599453f;   // ln(2)

typedef __attribute__((ext_vector_type(2))) float f32x2;

__device__ __forceinline__ f32x2 pk_fma(f32x2 a, f32x2 b, f32x2 c) {
    return __builtin_elementwise_fma(a, b, c);
}

// x + partner(l^1)'s x via DPP quad_perm [1,0,3,2] — no LDS roundtrip.
__device__ __forceinline__ float pair_sum(float x) {
    int sw = __builtin_amdgcn_update_dpp(0, __float_as_int(x),
                                         0xB1, 0xF, 0xF, true);
    return x + __int_as_float(sw);
}

// pull both halves of an f32x2 from lane (byte_addr >> 2)
__device__ __forceinline__ f32x2 bperm2(int byte_addr, f32x2 v) {
    f32x2 r;
    r.x = __int_as_float(
        __builtin_amdgcn_ds_bpermute(byte_addr, __float_as_int(v.x)));
    r.y = __int_as_float(
        __builtin_amdgcn_ds_bpermute(byte_addr, __float_as_int(v.y)));
    return r;
}

// Inline grid barrier: no function calls, regalloc stays leaf-clean.
// bar must be zeroed before launch (hipMemsetAsync in kernel_launch).
__device__ __forceinline__ void grid_barrier(unsigned* bar) {
    __syncthreads();                 // all waves' stores issued+drained
    if (threadIdx.x == 0) {
        __builtin_amdgcn_fence(__ATOMIC_RELEASE, "agent");   // L2 writeback
        __hip_atomic_fetch_add(bar, 1u, __ATOMIC_RELAXED,
                               __HIP_MEMORY_SCOPE_AGENT);
        while (__hip_atomic_load(bar, __ATOMIC_RELAXED,
                                 __HIP_MEMORY_SCOPE_AGENT) < (unsigned)kGrid) {
            __builtin_amdgcn_s_sleep(1);
        }
        __builtin_amdgcn_fence(__ATOMIC_ACQUIRE, "agent");   // L1/L2 inv
    }
    __syncthreads();
}

// One NCN layer for one (b,g,n) unit, executed by one wave.
// S: group stride (0 for stage 0, 1 for stage 1).
// IN_SCALED:  inputs already in scaled domain (Xi = L1*x, Ya = 0.1*L1*xa).
// OUT_SCALED: leave outputs in scaled domain (skip unscale).
template <int S, bool IN_SCALED, bool OUT_SCALED>
__device__ __forceinline__ void ncn_layer(
    const float* x_in, const float* xa_in, const float* Wl,
    float* x_out, float* xa_out, int unit, int l)
{
    const int n = unit & 3;
    const int g = (unit >> 2) & (kM - 1);
    const int b = unit >> 9;

    const int h = l & 1;                        // feat half: [h*16, h*16+16)
    const int r = l >> 1;                       // row in group, 0..31

    // global row: ((g + r*S) % m) * CACHE + r
    const int gr = (((g + r * S) & (kM - 1)) << 5) + r;
    const size_t base = ((size_t)(b * kN + gr)) * kE + n * kCE + h * 16;

    // state (scaled domain) + weights (pre-scaled by ln2 -> dots = TRUE sim)
    f32x2 xi[8], ya[8], wi[8], wj[8];
    {
        const float4* xi4 = reinterpret_cast<const float4*>(x_in + base);
        const float4* xa4 = reinterpret_cast<const float4*>(xa_in + base);
        const float4* wi4 = reinterpret_cast<const float4*>(Wl + n * kCE + h * 16);
        const float4* wj4 = reinterpret_cast<const float4*>(Wl + kE + n * kCE + h * 16);
#pragma unroll
        for (int q4 = 0; q4 < 4; ++q4) {
            float4 v = xi4[q4];
            float4 a = xa4[q4];
            if constexpr (IN_SCALED) {
                xi[2 * q4 + 0] = f32x2{v.x, v.y};
                xi[2 * q4 + 1] = f32x2{v.z, v.w};
                ya[2 * q4 + 0] = f32x2{a.x, a.y};
                ya[2 * q4 + 1] = f32x2{a.z, a.w};
            } else {
                xi[2 * q4 + 0] = f32x2{v.x * kL1, v.y * kL1};
                xi[2 * q4 + 1] = f32x2{v.z * kL1, v.w * kL1};
                ya[2 * q4 + 0] = f32x2{a.x * (0.1f * kL1), a.y * (0.1f * kL1)};
                ya[2 * q4 + 1] = f32x2{a.z * (0.1f * kL1), a.w * (0.1f * kL1)};
            }
            float4 u = wi4[q4];
            wi[2 * q4 + 0] = f32x2{u.x * kInvL1, u.y * kInvL1};
            wi[2 * q4 + 1] = f32x2{u.z * kInvL1, u.w * kInvL1};
            float4 w2 = wj4[q4];
            wj[2 * q4 + 0] = f32x2{w2.x * kInvL1, w2.y * kInvL1};
            wj[2 * q4 + 1] = f32x2{w2.z * kInvL1, w2.w * kInvL1};
        }
    }

    const int v4h = h << 2;                     // bpermute byte base (lane*4)

    const f32x2 one = {1.0f, 1.0f};
    const f32x2 c9  = {0.9f, 0.9f};
    const f32x2 cA  = {0.01f * kL1, 0.01f * kL1};      // + 0.01*L1
    const f32x2 cB  = {-0.02f * kL1, -0.02f * kL1};    // - 0.02*L1 * rc

#pragma unroll
    for (int j = 0; j < kCache; ++j) {
        // (1) pull row j's own-half feats from lanes 2j / 2j+1 (pre-update
        //     state: program order guarantees all lanes are at step j)
        const int addr = v4h + 8 * j;           // folds to offset imm
        f32x2 xj[8];
#pragma unroll
        for (int q = 0; q < 8; ++q) xj[q] = bperm2(addr, xi[q]);

        // (2) own-row dots over own 16 feats (true domain):
        //     a = xi_r . Wi   e = xi_r . Wj
        f32x2 a0 = xi[0] * wi[0], a1 = xi[1] * wi[1];
        f32x2 e0 = xi[0] * wj[0], e1 = xi[1] * wj[1];
        a0 = pk_fma(xi[2], wi[2], a0); a1 = pk_fma(xi[3], wi[3], a1);
        e0 = pk_fma(xi[2], wj[2], e0); e1 = pk_fma(xi[3], wj[3], e1);
        a0 = pk_fma(xi[4], wi[4], a0); a1 = pk_fma(xi[5], wi[5], a1);
        e0 = pk_fma(xi[4], wj[4], e0); e1 = pk_fma(xi[5], wj[5], e1);
        a0 = pk_fma(xi[6], wi[6], a0); a1 = pk_fma(xi[7], wi[7], a1);
        e0 = pk_fma(xi[6], wj[6], e0); e1 = pk_fma(xi[7], wj[7], e1);
        f32x2 av = a0 + a1, ev = e0 + e1;
        float a = av.x + av.y;
        float e = ev.x + ev.y;
        a = pair_sum(a);                        // full 32-feat row dot
        e = pair_sum(e);

        // (3) row j's Wj-dot: one readlane (lane 2j holds it), uniform scalar
        const float dj = __int_as_float(
            __builtin_amdgcn_readlane(__float_as_int(e), 2 * j));
        const float sim = a + dj;               // true sim for this row
        const f32x2 sv = {sim, sim};

        // (4) elementwise update in scaled domain
#pragma unroll
        for (int q = 0; q < 8; ++q) {
            f32x2 arg = pk_fma(xj[q], sv, xi[q]);   // L1*(xi + sim*xj) = L1*2T
            f32x2 t2;
            t2.x = __builtin_amdgcn_exp2f(arg.x);
            t2.y = __builtin_amdgcn_exp2f(arg.y);
            f32x2 den = t2 + one;
            f32x2 rc;
            rc.x = __builtin_amdgcn_rcpf(den.x);
            rc.y = __builtin_amdgcn_rcpf(den.y);
            // Ya' = 0.9*Ya + 0.01*L1 - 0.02*L1*rc   (Ya = 0.1*L1*xa)
            f32x2 yt = pk_fma(ya[q], c9, cA);
            ya[q] = pk_fma(rc, cB, yt);
            // Xi' = 0.9*Xi + Ya'
            xi[q] = pk_fma(xi[q], c9, ya[q]);
        }
    }

    // epilogue
    {
        float4* xo4 = reinterpret_cast<float4*>(x_out + base);
        float4* ao4 = reinterpret_cast<float4*>(xa_out + base);
#pragma unroll
        for (int q4 = 0; q4 < 4; ++q4) {
            f32x2 x0 = xi[2 * q4 + 0], x1 = xi[2 * q4 + 1];
            f32x2 a0 = ya[2 * q4 + 0], a1 = ya[2 * q4 + 1];
            if constexpr (!OUT_SCALED) {
                const f32x2 ivx = {kInvL1, kInvL1};
                const f32x2 iva = {10.0f * kInvL1, 10.0f * kInvL1};
                x0 = x0 * ivx; x1 = x1 * ivx;
                a0 = a0 * iva; a1 = a1 * iva;
            }
            float4 v; v.x = x0.x; v.y = x0.y; v.z = x1.x; v.w = x1.y;
            xo4[q4] = v;
            float4 w; w.x = a0.x; w.y = a0.y; w.z = a1.x; w.w = a1.y;
            ao4[q4] = w;
        }
    }
}
}  // namespace

__global__ void __launch_bounds__(256, 2) ncn_fused_kernel(
    const float* __restrict__ x, const float* __restrict__ xa,
    const float* __restrict__ W,
    float* __restrict__ xo, float* __restrict__ ao,
    unsigned* __restrict__ bar)
{
    const int t = threadIdx.x;
    const int unit = blockIdx.x * 4 + (t >> 6);   // (b, g, n), 0..2047
    const int l = t & 63;

    // Layer 0 (stage 0): d_in -> d_out, scaled-domain mid-state.
    ncn_layer<0, false, true>(x, xa, W, xo, ao, unit, l);

    // Inline grid barrier (device-scope release/acquire, cross-XCD safe).
    grid_barrier(bar);

    // Layer 1 (stage 1): d_out -> d_out in-place (reader == writer per addr).
    ncn_layer<1, true, false>(xo, ao, W + 2 * kE, xo, ao, unit, l);
}

extern "C" void kernel_launch(void* const* d_in, const int* in_sizes, int n_in,
                              void* d_out, int out_size, void* d_ws, size_t ws_size,
                              hipStream_t stream) {
    const float* x  = (const float*)d_in[0];   // [B, N, E] fp32
    const float* xa = (const float*)d_in[1];   // [B, N, E] fp32
    const float* W  = (const float*)d_in[2];   // [2, 256] fp32

    const size_t plane = (size_t)kB * kN * kE;   // 2,097,152 floats (8 MiB)

    float* x_out  = (float*)d_out;               // final outputs
    float* xa_out = x_out + plane;

    unsigned* bar = (unsigned*)d_ws;             // barrier counter

    // zero the barrier counter each launch (async, graph-capturable)
    hipMemsetAsync(bar, 0, 64, stream);

    // 512 blocks x 256 threads = 2048 waves = 2 blocks/CU, exactly co-resident.
    void* args[6] = {(void*)&x, (void*)&xa, (void*)&W,
                     (void*)&x_out, (void*)&xa_out, (void*)&bar};
    hipLaunchCooperativeKernel((const void*)ncn_fused_kernel,
                               dim3(kGrid), dim3(256), args, 0, stream);
}

// Round 4
// 182.624 us; speedup vs baseline: 1.3551x; 1.0181x over previous
//
#include <hip/hip_runtime.h>

// NCN recurrence, 2 layers. B=4, N=4096, E=128, NK=4, ce=32, CACHE=32, m=128.
// 2048 independent [32 rows x 32 feats] subproblems per layer.
//
// R13: KILL THE SPILL + CHEAP BARRIER. R12 evidence: VGPR_Count=60 with
// ~110 live values needed, and VALUBusy-derived instruction count ~5x the
// algorithmic VALU work -> state is in scratch; per-layer time pinned at
// ~30us across R9/R10/R11/R12 which all shared (a) occupancy-capping
// launch_bounds and (b) fully-unrolled 32-step bodies (~3-6k instrs,
// I-cache is 32KB). Fixes:
//   1. __launch_bounds__(256) only — no second arg, no VGPR cap. Even at
//      256 VGPR the cooperative launch still fits 2 blocks/CU = 512 exact.
//   2. #pragma unroll 4 on the step loop: ~1k instrs/layer, I-cache
//      resident, lower regalloc pressure. readlane lane idx stays uniform.
//   3. Grid barrier: last arriver broadcasts a release flag; waiters poll
//      the flag (read-only line) with s_sleep(2) backoff — no 512-way RMW
//      congestion during the wait phase.
// Structure otherwise = R12: fused two layers, layer0 d_in->d_out (scaled
// domain), inline grid barrier, layer1 in-place on d_out (bijection:
// reader == writer per address). d_ws holds 2 barrier words, zeroed by
// hipMemsetAsync each launch (graph-capturable).
//
// Per-layer core (R10): wave-autonomous groups. lane l: row r=l>>1, feat
// half h=l&1 (16 feats = 8 f32x2). Row-j broadcast via 16x ds_bpermute;
// pair reduce via DPP quad_perm; row-j Wj-dot via v_readlane. Scaled
// domain: Xi=L1*xi, Ya=0.1*L1*xa, W pre-scaled by ln2; tanh = 1 -
// 2/(exp2(arg)+1), arg = Xi + sim*Xj (exact +-1 at exp2 overflow).

namespace {
constexpr int kB = 4;
constexpr int kN = 4096;
constexpr int kE = 128;
constexpr int kCE = 32;          // E / NK
constexpr int kCache = 32;
constexpr int kM = kN / kCache;  // 128 groups per batch
constexpr int kGrid = kB * kM;   // 512 blocks

constexpr float kL1    = 1.4426950408889634f;   // log2(e)
constexpr float kInvL1 = 0.6931471805599453f;   // ln(2)

typedef __attribute__((ext_vector_type(2))) float f32x2;

__device__ __forceinline__ f32x2 pk_fma(f32x2 a, f32x2 b, f32x2 c) {
    return __builtin_elementwise_fma(a, b, c);
}

// x + partner(l^1)'s x via DPP quad_perm [1,0,3,2] — no LDS roundtrip.
__device__ __forceinline__ float pair_sum(float x) {
    int sw = __builtin_amdgcn_update_dpp(0, __float_as_int(x),
                                         0xB1, 0xF, 0xF, true);
    return x + __int_as_float(sw);
}

// pull both halves of an f32x2 from lane (byte_addr >> 2)
__device__ __forceinline__ f32x2 bperm2(int byte_addr, f32x2 v) {
    f32x2 r;
    r.x = __int_as_float(
        __builtin_amdgcn_ds_bpermute(byte_addr, __float_as_int(v.x)));
    r.y = __int_as_float(
        __builtin_amdgcn_ds_bpermute(byte_addr, __float_as_int(v.y)));
    return r;
}

// Inline grid barrier, release-flag design. bar[0]=arrival count,
// bar[16]=release flag; both zeroed before launch via hipMemsetAsync.
__device__ __forceinline__ void grid_barrier(unsigned* bar) {
    __syncthreads();                 // all waves' stores issued+drained
    if (threadIdx.x == 0) {
        unsigned* cnt = bar;
        unsigned* rel = bar + 16;    // separate dword, same zeroed region
        __builtin_amdgcn_fence(__ATOMIC_RELEASE, "agent");   // L2 writeback
        unsigned old = __hip_atomic_fetch_add(cnt, 1u, __ATOMIC_RELAXED,
                                              __HIP_MEMORY_SCOPE_AGENT);
        if (old == (unsigned)(kGrid - 1)) {
            // last arriver: broadcast release
            __hip_atomic_store(rel, 1u, __ATOMIC_RELEASE,
                               __HIP_MEMORY_SCOPE_AGENT);
        } else {
            while (__hip_atomic_load(rel, __ATOMIC_RELAXED,
                                     __HIP_MEMORY_SCOPE_AGENT) == 0u) {
                __builtin_amdgcn_s_sleep(2);
            }
        }
        __builtin_amdgcn_fence(__ATOMIC_ACQUIRE, "agent");   // L1/L2 inv
    }
    __syncthreads();
}

// One NCN layer for one (b,g,n) unit, executed by one wave.
// S: group stride (0 for stage 0, 1 for stage 1).
// IN_SCALED:  inputs already in scaled domain (Xi = L1*x, Ya = 0.1*L1*xa).
// OUT_SCALED: leave outputs in scaled domain (skip unscale).
template <int S, bool IN_SCALED, bool OUT_SCALED>
__device__ __forceinline__ void ncn_layer(
    const float* x_in, const float* xa_in, const float* Wl,
    float* x_out, float* xa_out, int unit, int l)
{
    const int n = unit & 3;
    const int g = (unit >> 2) & (kM - 1);
    const int b = unit >> 9;

    const int h = l & 1;                        // feat half: [h*16, h*16+16)
    const int r = l >> 1;                       // row in group, 0..31

    // global row: ((g + r*S) % m) * CACHE + r
    const int gr = (((g + r * S) & (kM - 1)) << 5) + r;
    const size_t base = ((size_t)(b * kN + gr)) * kE + n * kCE + h * 16;

    // state (scaled domain) + weights (pre-scaled by ln2 -> dots = TRUE sim)
    f32x2 xi[8], ya[8], wi[8], wj[8];
    {
        const float4* xi4 = reinterpret_cast<const float4*>(x_in + base);
        const float4* xa4 = reinterpret_cast<const float4*>(xa_in + base);
        const float4* wi4 = reinterpret_cast<const float4*>(Wl + n * kCE + h * 16);
        const float4* wj4 = reinterpret_cast<const float4*>(Wl + kE + n * kCE + h * 16);
#pragma unroll
        for (int q4 = 0; q4 < 4; ++q4) {
            float4 v = xi4[q4];
            float4 a = xa4[q4];
            if constexpr (IN_SCALED) {
                xi[2 * q4 + 0] = f32x2{v.x, v.y};
                xi[2 * q4 + 1] = f32x2{v.z, v.w};
                ya[2 * q4 + 0] = f32x2{a.x, a.y};
                ya[2 * q4 + 1] = f32x2{a.z, a.w};
            } else {
                xi[2 * q4 + 0] = f32x2{v.x * kL1, v.y * kL1};
                xi[2 * q4 + 1] = f32x2{v.z * kL1, v.w * kL1};
                ya[2 * q4 + 0] = f32x2{a.x * (0.1f * kL1), a.y * (0.1f * kL1)};
                ya[2 * q4 + 1] = f32x2{a.z * (0.1f * kL1), a.w * (0.1f * kL1)};
            }
            float4 u = wi4[q4];
            wi[2 * q4 + 0] = f32x2{u.x * kInvL1, u.y * kInvL1};
            wi[2 * q4 + 1] = f32x2{u.z * kInvL1, u.w * kInvL1};
            float4 w2 = wj4[q4];
            wj[2 * q4 + 0] = f32x2{w2.x * kInvL1, w2.y * kInvL1};
            wj[2 * q4 + 1] = f32x2{w2.z * kInvL1, w2.w * kInvL1};
        }
    }

    const int v4h = h << 2;                     // bpermute byte base (lane*4)

    const f32x2 one = {1.0f, 1.0f};
    const f32x2 c9  = {0.9f, 0.9f};
    const f32x2 cA  = {0.01f * kL1, 0.01f * kL1};      // + 0.01*L1
    const f32x2 cB  = {-0.02f * kL1, -0.02f * kL1};    // - 0.02*L1 * rc

    // Partial unroll: ~400 instrs per unrolled group, I-cache resident,
    // low regalloc pressure. j stays wave-uniform -> readlane idx in SGPR.
#pragma unroll 4
    for (int j = 0; j < kCache; ++j) {
        // (1) pull row j's own-half feats from lanes 2j / 2j+1 (pre-update
        //     state: program order guarantees all lanes are at step j)
        const int addr = v4h + 8 * j;
        f32x2 xj[8];
#pragma unroll
        for (int q = 0; q < 8; ++q) xj[q] = bperm2(addr, xi[q]);

        // (2) own-row dots over own 16 feats (true domain):
        //     a = xi_r . Wi   e = xi_r . Wj
        f32x2 a0 = xi[0] * wi[0], a1 = xi[1] * wi[1];
        f32x2 e0 = xi[0] * wj[0], e1 = xi[1] * wj[1];
        a0 = pk_fma(xi[2], wi[2], a0); a1 = pk_fma(xi[3], wi[3], a1);
        e0 = pk_fma(xi[2], wj[2], e0); e1 = pk_fma(xi[3], wj[3], e1);
        a0 = pk_fma(xi[4], wi[4], a0); a1 = pk_fma(xi[5], wi[5], a1);
        e0 = pk_fma(xi[4], wj[4], e0); e1 = pk_fma(xi[5], wj[5], e1);
        a0 = pk_fma(xi[6], wi[6], a0); a1 = pk_fma(xi[7], wi[7], a1);
        e0 = pk_fma(xi[6], wj[6], e0); e1 = pk_fma(xi[7], wj[7], e1);
        f32x2 av = a0 + a1, ev = e0 + e1;
        float a = av.x + av.y;
        float e = ev.x + ev.y;
        a = pair_sum(a);                        // full 32-feat row dot
        e = pair_sum(e);

        // (3) row j's Wj-dot: one readlane (lane 2j holds it), uniform scalar
        const float dj = __int_as_float(
            __builtin_amdgcn_readlane(__float_as_int(e), 2 * j));
        const float sim = a + dj;               // true sim for this row
        const f32x2 sv = {sim, sim};

        // (4) elementwise update in scaled domain
#pragma unroll
        for (int q = 0; q < 8; ++q) {
            f32x2 arg = pk_fma(xj[q], sv, xi[q]);   // L1*(xi + sim*xj) = L1*2T
            f32x2 t2;
            t2.x = __builtin_amdgcn_exp2f(arg.x);
            t2.y = __builtin_amdgcn_exp2f(arg.y);
            f32x2 den = t2 + one;
            f32x2 rc;
            rc.x = __builtin_amdgcn_rcpf(den.x);
            rc.y = __builtin_amdgcn_rcpf(den.y);
            // Ya' = 0.9*Ya + 0.01*L1 - 0.02*L1*rc   (Ya = 0.1*L1*xa)
            f32x2 yt = pk_fma(ya[q], c9, cA);
            ya[q] = pk_fma(rc, cB, yt);
            // Xi' = 0.9*Xi + Ya'
            xi[q] = pk_fma(xi[q], c9, ya[q]);
        }
    }

    // epilogue
    {
        float4* xo4 = reinterpret_cast<float4*>(x_out + base);
        float4* ao4 = reinterpret_cast<float4*>(xa_out + base);
#pragma unroll
        for (int q4 = 0; q4 < 4; ++q4) {
            f32x2 x0 = xi[2 * q4 + 0], x1 = xi[2 * q4 + 1];
            f32x2 a0 = ya[2 * q4 + 0], a1 = ya[2 * q4 + 1];
            if constexpr (!OUT_SCALED) {
                const f32x2 ivx = {kInvL1, kInvL1};
                const f32x2 iva = {10.0f * kInvL1, 10.0f * kInvL1};
                x0 = x0 * ivx; x1 = x1 * ivx;
                a0 = a0 * iva; a1 = a1 * iva;
            }
            float4 v; v.x = x0.x; v.y = x0.y; v.z = x1.x; v.w = x1.y;
            xo4[q4] = v;
            float4 w; w.x = a0.x; w.y = a0.y; w.z = a1.x; w.w = a1.y;
            ao4[q4] = w;
        }
    }
}
}  // namespace

__global__ void __launch_bounds__(256) ncn_fused_kernel(
    const float* __restrict__ x, const float* __restrict__ xa,
    const float* __restrict__ W,
    float* __restrict__ xo, float* __restrict__ ao,
    unsigned* __restrict__ bar)
{
    const int t = threadIdx.x;
    const int unit = blockIdx.x * 4 + (t >> 6);   // (b, g, n), 0..2047
    const int l = t & 63;

    // Layer 0 (stage 0): d_in -> d_out, scaled-domain mid-state.
    ncn_layer<0, false, true>(x, xa, W, xo, ao, unit, l);

    // Inline grid barrier (device-scope release/acquire, cross-XCD safe).
    grid_barrier(bar);

    // Layer 1 (stage 1): d_out -> d_out in-place (reader == writer per addr).
    ncn_layer<1, true, false>(xo, ao, W + 2 * kE, xo, ao, unit, l);
}

extern "C" void kernel_launch(void* const* d_in, const int* in_sizes, int n_in,
                              void* d_out, int out_size, void* d_ws, size_t ws_size,
                              hipStream_t stream) {
    const float* x  = (const float*)d_in[0];   // [B, N, E] fp32
    const float* xa = (const float*)d_in[1];   // [B, N, E] fp32
    const float* W  = (const float*)d_in[2];   // [2, 256] fp32

    const size_t plane = (size_t)kB * kN * kE;   // 2,097,152 floats (8 MiB)

    float* x_out  = (float*)d_out;               // final outputs
    float* xa_out = x_out + plane;

    unsigned* bar = (unsigned*)d_ws;             // barrier words (count, rel)

    // zero the barrier words each launch (async, graph-capturable)
    hipMemsetAsync(bar, 0, 128, stream);

    // 512 blocks x 256 threads = 2048 waves = 2 blocks/CU, co-resident.
    void* args[6] = {(void*)&x, (void*)&xa, (void*)&W,
                     (void*)&x_out, (void*)&xa_out, (void*)&bar};
    hipLaunchCooperativeKernel((const void*)ncn_fused_kernel,
                               dim3(kGrid), dim3(256), args, 0, stream);
}

// Round 5
// 117.138 us; speedup vs baseline: 2.1127x; 1.5590x over previous
//
#include <hip/hip_runtime.h>

// NCN recurrence, 2 layers. B=4, N=4096, E=128, NK=4, ce=32, CACHE=32, m=128.
// 2048 independent [32 rows x 32 feats] subproblems per layer.
//
// R14: DEFUSE + PIN WAVES-PER-EU. Evidence chain:
//  - R13 (no launch_bounds cap): VGPR_Count=56 ~= 512/10 (default wpe max);
//    R11/R12 (min=2): 60 ~= 512/8. The scheduler targets the MAX of the
//    waves-per-eu range and squeezes arch-VGPR pressure via AGPR shuffle
//    copies (v_accvgpr_*): no scratch traffic (FETCH=16.5MB=x+xa exactly)
//    but VALU inflated 508 vs ~276 algorithmic cyc/step.
//  - We have exactly 2048 waves of work = 2/SIMD; occupancy >2 is
//    unreachable. __attribute__((amdgpu_waves_per_eu(2,2))): budget 256
//    VGPRs, scheduler stops shuffling. Live state ~110 regs fits.
//  - Fused+grid-barrier (R12/R13, 100-102us) is ~2x WORSE than R10's two
//    dispatches (~44us combined): 512 per-block agent fences (L2 writeback
//    + invalidate) + arrival skew cost ~50us, fusion saved ~7us. Defuse.
// Kept from R11-R13: scaled-domain mid-state in d_ws (layer 0 skips
// unscale, layer 1 skips rescale - 4 fewer VALU passes vs R10).
//
// Per-layer core (R10): wave-autonomous groups, one wave64 = one (b,g,n).
//   lane l: row r=l>>1, feat half h=l&1 (16 feats = 8 f32x2).
//   row-j broadcast: 16x ds_bpermute (imm-folded addr), no LDS/barriers.
//   pair reduce via DPP quad_perm; row-j Wj-dot via v_readlane (imm lane).
//   scaled domain: Xi=L1*xi, Ya=0.1*L1*xa, W pre-scaled by ln2;
//   tanh = 1 - 2/(exp2(arg)+1), arg = Xi + sim*Xj (exact +-1 at overflow).

namespace {
constexpr int kB = 4;
constexpr int kN = 4096;
constexpr int kE = 128;
constexpr int kCE = 32;          // E / NK
constexpr int kCache = 32;
constexpr int kM = kN / kCache;  // 128 groups per batch

constexpr float kL1    = 1.4426950408889634f;   // log2(e)
constexpr float kInvL1 = 0.6931471805599453f;   // ln(2)

typedef __attribute__((ext_vector_type(2))) float f32x2;

__device__ __forceinline__ f32x2 pk_fma(f32x2 a, f32x2 b, f32x2 c) {
    return __builtin_elementwise_fma(a, b, c);
}

// x + partner(l^1)'s x via DPP quad_perm [1,0,3,2] — no LDS roundtrip.
__device__ __forceinline__ float pair_sum(float x) {
    int sw = __builtin_amdgcn_update_dpp(0, __float_as_int(x),
                                         0xB1, 0xF, 0xF, true);
    return x + __int_as_float(sw);
}

// pull both halves of an f32x2 from lane (byte_addr >> 2)
__device__ __forceinline__ f32x2 bperm2(int byte_addr, f32x2 v) {
    f32x2 r;
    r.x = __int_as_float(
        __builtin_amdgcn_ds_bpermute(byte_addr, __float_as_int(v.x)));
    r.y = __int_as_float(
        __builtin_amdgcn_ds_bpermute(byte_addr, __float_as_int(v.y)));
    return r;
}
}  // namespace

// S: group stride (0 for stage 0, 1 for stage 1).
// IN_SCALED:  inputs already in scaled domain (Xi = L1*x, Ya = 0.1*L1*xa).
// OUT_SCALED: leave outputs in scaled domain (skip unscale).
template <int S, bool IN_SCALED, bool OUT_SCALED>
__global__ void __launch_bounds__(256)
__attribute__((amdgpu_waves_per_eu(2, 2)))
ncn_layer_kernel(const float* __restrict__ x_in,
                 const float* __restrict__ xa_in,
                 const float* __restrict__ Wl,   // this layer's 256 floats
                 float* __restrict__ x_out,
                 float* __restrict__ xa_out)
{
    const int t    = threadIdx.x;
    const int unit = blockIdx.x * 4 + (t >> 6);   // (b, g, n), 0..2047
    const int l    = t & 63;

    const int n = unit & 3;
    const int g = (unit >> 2) & (kM - 1);
    const int b = unit >> 9;

    const int h = l & 1;                        // feat half: [h*16, h*16+16)
    const int r = l >> 1;                       // row in group, 0..31

    // global row: ((g + r*S) % m) * CACHE + r
    const int gr = (((g + r * S) & (kM - 1)) << 5) + r;
    const size_t base = ((size_t)(b * kN + gr)) * kE + n * kCE + h * 16;

    // state (scaled domain) + weights (pre-scaled by ln2 -> dots = TRUE sim)
    f32x2 xi[8], ya[8], wi[8], wj[8];
    {
        const float4* xi4 = reinterpret_cast<const float4*>(x_in + base);
        const float4* xa4 = reinterpret_cast<const float4*>(xa_in + base);
        const float4* wi4 = reinterpret_cast<const float4*>(Wl + n * kCE + h * 16);
        const float4* wj4 = reinterpret_cast<const float4*>(Wl + kE + n * kCE + h * 16);
#pragma unroll
        for (int q4 = 0; q4 < 4; ++q4) {
            float4 v = xi4[q4];
            float4 a = xa4[q4];
            if constexpr (IN_SCALED) {
                xi[2 * q4 + 0] = f32x2{v.x, v.y};
                xi[2 * q4 + 1] = f32x2{v.z, v.w};
                ya[2 * q4 + 0] = f32x2{a.x, a.y};
                ya[2 * q4 + 1] = f32x2{a.z, a.w};
            } else {
                xi[2 * q4 + 0] = f32x2{v.x * kL1, v.y * kL1};
                xi[2 * q4 + 1] = f32x2{v.z * kL1, v.w * kL1};
                ya[2 * q4 + 0] = f32x2{a.x * (0.1f * kL1), a.y * (0.1f * kL1)};
                ya[2 * q4 + 1] = f32x2{a.z * (0.1f * kL1), a.w * (0.1f * kL1)};
            }
            float4 u = wi4[q4];
            wi[2 * q4 + 0] = f32x2{u.x * kInvL1, u.y * kInvL1};
            wi[2 * q4 + 1] = f32x2{u.z * kInvL1, u.w * kInvL1};
            float4 w2 = wj4[q4];
            wj[2 * q4 + 0] = f32x2{w2.x * kInvL1, w2.y * kInvL1};
            wj[2 * q4 + 1] = f32x2{w2.z * kInvL1, w2.w * kInvL1};
        }
    }

    const int v4h = h << 2;                     // bpermute byte base (lane*4)

    const f32x2 one = {1.0f, 1.0f};
    const f32x2 c9  = {0.9f, 0.9f};
    const f32x2 cA  = {0.01f * kL1, 0.01f * kL1};      // + 0.01*L1
    const f32x2 cB  = {-0.02f * kL1, -0.02f * kL1};    // - 0.02*L1 * rc

#pragma unroll
    for (int j = 0; j < kCache; ++j) {
        // (1) pull row j's own-half feats from lanes 2j / 2j+1 (pre-update
        //     state: program order guarantees all lanes are at step j)
        const int addr = v4h + 8 * j;           // folds to offset imm
        f32x2 xj[8];
#pragma unroll
        for (int q = 0; q < 8; ++q) xj[q] = bperm2(addr, xi[q]);

        // (2) own-row dots over own 16 feats (true domain):
        //     a = xi_r . Wi   e = xi_r . Wj
        f32x2 a0 = xi[0] * wi[0], a1 = xi[1] * wi[1];
        f32x2 e0 = xi[0] * wj[0], e1 = xi[1] * wj[1];
        a0 = pk_fma(xi[2], wi[2], a0); a1 = pk_fma(xi[3], wi[3], a1);
        e0 = pk_fma(xi[2], wj[2], e0); e1 = pk_fma(xi[3], wj[3], e1);
        a0 = pk_fma(xi[4], wi[4], a0); a1 = pk_fma(xi[5], wi[5], a1);
        e0 = pk_fma(xi[4], wj[4], e0); e1 = pk_fma(xi[5], wj[5], e1);
        a0 = pk_fma(xi[6], wi[6], a0); a1 = pk_fma(xi[7], wi[7], a1);
        e0 = pk_fma(xi[6], wj[6], e0); e1 = pk_fma(xi[7], wj[7], e1);
        f32x2 av = a0 + a1, ev = e0 + e1;
        float a = av.x + av.y;
        float e = ev.x + ev.y;
        a = pair_sum(a);                        // full 32-feat row dot
        e = pair_sum(e);

        // (3) row j's Wj-dot: one readlane (lane 2j holds it), uniform scalar
        const float dj = __int_as_float(
            __builtin_amdgcn_readlane(__float_as_int(e), 2 * j));
        const float sim = a + dj;               // true sim for this row
        const f32x2 sv = {sim, sim};

        // (4) elementwise update in scaled domain
#pragma unroll
        for (int q = 0; q < 8; ++q) {
            f32x2 arg = pk_fma(xj[q], sv, xi[q]);   // L1*(xi + sim*xj) = L1*2T
            f32x2 t2;
            t2.x = __builtin_amdgcn_exp2f(arg.x);
            t2.y = __builtin_amdgcn_exp2f(arg.y);
            f32x2 den = t2 + one;
            f32x2 rc;
            rc.x = __builtin_amdgcn_rcpf(den.x);
            rc.y = __builtin_amdgcn_rcpf(den.y);
            // Ya' = 0.9*Ya + 0.01*L1 - 0.02*L1*rc   (Ya = 0.1*L1*xa)
            f32x2 yt = pk_fma(ya[q], c9, cA);
            ya[q] = pk_fma(rc, cB, yt);
            // Xi' = 0.9*Xi + Ya'
            xi[q] = pk_fma(xi[q], c9, ya[q]);
        }
    }

    // epilogue
    {
        float4* xo4 = reinterpret_cast<float4*>(x_out + base);
        float4* ao4 = reinterpret_cast<float4*>(xa_out + base);
#pragma unroll
        for (int q4 = 0; q4 < 4; ++q4) {
            f32x2 x0 = xi[2 * q4 + 0], x1 = xi[2 * q4 + 1];
            f32x2 a0 = ya[2 * q4 + 0], a1 = ya[2 * q4 + 1];
            if constexpr (!OUT_SCALED) {
                const f32x2 ivx = {kInvL1, kInvL1};
                const f32x2 iva = {10.0f * kInvL1, 10.0f * kInvL1};
                x0 = x0 * ivx; x1 = x1 * ivx;
                a0 = a0 * iva; a1 = a1 * iva;
            }
            float4 v; v.x = x0.x; v.y = x0.y; v.z = x1.x; v.w = x1.y;
            xo4[q4] = v;
            float4 w; w.x = a0.x; w.y = a0.y; w.z = a1.x; w.w = a1.y;
            ao4[q4] = w;
        }
    }
}

extern "C" void kernel_launch(void* const* d_in, const int* in_sizes, int n_in,
                              void* d_out, int out_size, void* d_ws, size_t ws_size,
                              hipStream_t stream) {
    const float* x  = (const float*)d_in[0];   // [B, N, E] fp32
    const float* xa = (const float*)d_in[1];   // [B, N, E] fp32
    const float* W  = (const float*)d_in[2];   // [2, 256] fp32

    const size_t plane = (size_t)kB * kN * kE;   // 2,097,152 floats (8 MiB)

    float* x_mid  = (float*)d_ws;                // scaled-domain mid-state
    float* xa_mid = x_mid + plane;               // (16 MiB total in ws)

    float* x_out  = (float*)d_out;               // final outputs
    float* xa_out = x_out + plane;

    const dim3 grid(kB * kM);   // 512 blocks x 4 waves = 2048 waves = 2/SIMD
    const dim3 block(256);

    // Layer 0 (stage 0): d_in -> ws, scaled domain   (pure, idempotent)
    ncn_layer_kernel<0, false, true><<<grid, block, 0, stream>>>(
        x, xa, W, x_mid, xa_mid);
    // Layer 1 (stage 1): ws -> d_out, unscaled       (pure, idempotent)
    ncn_layer_kernel<1, true, false><<<grid, block, 0, stream>>>(
        x_mid, xa_mid, W + 2 * kE, x_out, xa_out);
}